// Round 4
// baseline (141.473 us; speedup 1.0000x reference)
//
#include <hip/hip_runtime.h>
#include <hip/hip_bf16.h>
#include <math.h>

// Dims: B=8, T=1048576, V=257, E=8, C=128, K=512, S=512, N=64
// GEMM view: M=16384, Kdim=4096, Ncols=256 (w1 cols 0-127, w2 cols 128-255)
// R4: fix prep_w write loop (it<8, was it<4 -> half of each B-tile left as
//     poison). Structure identical to R3: x-scatter eliminated via prep_x
//     transpose; gemm BM=256, BN=128, ksplit=4, wave-tile 64x128, B DB.

typedef __bf16 bf16x8 __attribute__((ext_vector_type(8)));
typedef float  f32x4  __attribute__((ext_vector_type(4)));

// ---------------- ws layout ----------------
// [0,2MB)     Wp bf16 [nt2][sg32][tt4][q4][n128][e8]   (byte = sg*16+tt*4+q)
// [2MB,+8KB)  emb bf16 [257][8]
// [4MB,+16MB) xp u16 [mt64][kh4][st8][wave4][lane64][rg4][tt4]
// [24MB,+64MB) Cbuf fp32 [kh4][16384][256]
#define WS_WP_OFF   0u
#define WS_EMB_OFF  (2u << 20)
#define WS_XP_OFF   (4u << 20)
#define WS_C_OFF    (24u << 20)

__device__ __forceinline__ void load_lds16(const void* g, void* l) {
    __builtin_amdgcn_global_load_lds(
        (const __attribute__((address_space(1))) void*)g,
        (__attribute__((address_space(3))) void*)l,
        16, 0, 0);
}

// ---------------------------------------------------------------------------
// prep_w: 65 blocks. bid<64: (nt=bid>>5, sg=bid&31) packs one 32KB stage chunk
// [tt4][q4][n128][e8], value = w[nt][c=n][e][byte=sg*16+tt*4+q]. LDS transpose:
// coalesced float4 reads, b128 LDS reads, coalesced uint4 writes.
// ---------------------------------------------------------------------------
__global__ void prep_w(const float* __restrict__ w1,
                       const float* __restrict__ w2,
                       const float* __restrict__ emb,
                       uint4* __restrict__ Wp4,
                       __bf16* __restrict__ embp) {
    int bid = blockIdx.x, tid = threadIdx.x;
    if (bid < 64) {
        __shared__ __bf16 lds[16384];   // [n128][byte16][e8]
        int nt = bid >> 5, sg = bid & 31;
        const float* wsrc = nt ? w2 : w1;
#pragma unroll
        for (int i = 0; i < 16; ++i) {
            int g = i * 256 + tid;
            int j4 = g & 3, pair = g >> 2;
            int e = pair & 7, cl = pair >> 3;
            float4 v = *(const float4*)(wsrc + cl * 4096 + e * 512 + sg * 16 + j4 * 4);
            float vv[4] = {v.x, v.y, v.z, v.w};
#pragma unroll
            for (int jj = 0; jj < 4; ++jj)
                lds[(cl * 16 + j4 * 4 + jj) * 8 + e] = (__bf16)vv[jj];
        }
        __syncthreads();
        const uint4* l4 = (const uint4*)lds;
#pragma unroll
        for (int it = 0; it < 8; ++it) {               // R4 fix: 8*256 = 2048
            int j = it * 256 + tid;                    // chunk = (tt*4+q)*128 + n
            int n = j & 127, q = (j >> 7) & 3, tt = (j >> 9) & 3;
            Wp4[bid * 2048 + j] = l4[n * 16 + tt * 4 + q];
        }
    } else {
        for (int i = tid; i < 2056; i += 256) embp[i] = (__bf16)emb[i];
    }
}

// ---------------------------------------------------------------------------
// prep_x: 256 blocks = (mt64, kh4). Reads 256 rows x 128 bytes coalesced,
// LDS-transposes to u16 in gemm consumption order:
// xp slab [st8][wave4][lane64][rg4][tt4], idx = x[row(wave,rg,nl)][st*16+tt*4+q]
// ---------------------------------------------------------------------------
__global__ void prep_x(const int* __restrict__ x,
                       unsigned short* __restrict__ xp) {
    __shared__ unsigned short lds[256 * 136];   // padded row stride
    int bid = blockIdx.x, tid = threadIdx.x;
    int mt = bid >> 2, kh = bid & 3;
    const long src0 = (long)mt * 131072 + kh * 128;   // mt*256 rows * 512 + kh*128
#pragma unroll
    for (int i = 0; i < 32; ++i) {
        int f = i * 256 + tid;                   // int4 id: 8192 total
        int row = f >> 5, c = (f & 31) * 4;
        int4 v = *(const int4*)(x + src0 + (long)row * 512 + c);
        ushort4 s;
        s.x = (unsigned short)v.x; s.y = (unsigned short)v.y;
        s.z = (unsigned short)v.z; s.w = (unsigned short)v.w;
        *(ushort4*)&lds[row * 136 + c] = s;
    }
    __syncthreads();
    unsigned short* dst = xp + (size_t)bid * 32768;
#pragma unroll
    for (int i = 0; i < 32; ++i) {
        int jc = i * 256 + tid;                  // 8-B chunk: ((st*4+w)*64+lane)*4+rg
        int rg = jc & 3, lane = (jc >> 2) & 63, wv = (jc >> 8) & 3, st = jc >> 10;
        int q = lane >> 4, nl = lane & 15;
        int row = wv * 64 + rg * 16 + nl;
        int cb = st * 16 + q;
        ushort4 s;
        s.x = lds[row * 136 + cb];
        s.y = lds[row * 136 + cb + 4];
        s.z = lds[row * 136 + cb + 8];
        s.w = lds[row * 136 + cb + 12];
        *(ushort4*)&dst[jc * 4] = s;
    }
}

// ---------------------------------------------------------------------------
// gemm: 512 blocks = (mt64, kh4, nt2). BM=256, BN=128, 4 waves, wave 64x128.
// Kchunk=1024 hw-k = 8 stages of 128 hw-k. B DB 2x32KB, staged a full stage
// ahead (barrier drain ~0). A-frags gathered from LDS emb table via xp idx.
// ---------------------------------------------------------------------------
__global__ __launch_bounds__(256, 2)
void gemm_kernel(const unsigned short* __restrict__ xp,
                 const __bf16* __restrict__ Wp,
                 const uint4* __restrict__ embp,
                 float* __restrict__ Cbuf) {
    __shared__ uint4 ldsB[2][2048];   // 2 x 32KB: [tt4][q4][n128][e8]
    __shared__ uint4 embl[257];

    const int tid = threadIdx.x;
    const int wv = tid >> 6, lane = tid & 63;
    const int q = lane >> 4, nl = lane & 15;

    for (int i = tid; i < 257; i += 256) embl[i] = embp[i];

    const int bid = blockIdx.x;
    const int mt = bid >> 3, nt = bid & 1, kh = (bid >> 1) & 3;
    const int m0 = mt << 8;

    const char* WpBase = (const char*)Wp + (size_t)(nt * 32 + kh * 8) * 32768;
    const unsigned short* xpS = xp + (size_t)(mt * 4 + kh) * 32768 + (wv * 64 + lane) * 16;

    // prologue: stage B(0), load xp(0)
    {
        const char* src = WpBase + tid * 16;
        char* dstl = (char*)&ldsB[0][0] + tid * 16;
#pragma unroll
        for (int i = 0; i < 8; ++i) load_lds16(src + i * 4096, dstl + i * 4096);
    }
    uint4 xa = *(const uint4*)(xpS);
    uint4 xb = *(const uint4*)(xpS + 8);
    __syncthreads();

    f32x4 acc[4][8] = {};

    for (int st = 0; st < 8; ++st) {
        const int buf = st & 1;
        uint4 xa_n = xa, xb_n = xb;
        if (st < 7) {   // prefetch next stage: B -> other buffer, xp -> regs
            const char* src = WpBase + (size_t)(st + 1) * 32768 + tid * 16;
            char* dstl = (char*)&ldsB[buf ^ 1][0] + tid * 16;
#pragma unroll
            for (int i = 0; i < 8; ++i) load_lds16(src + i * 4096, dstl + i * 4096);
            const unsigned short* xn = xpS + (size_t)(st + 1) * 4096;
            xa_n = *(const uint4*)(xn);
            xb_n = *(const uint4*)(xn + 8);
        }
        const unsigned int u[8] = {xa.x, xa.y, xa.z, xa.w, xb.x, xb.y, xb.z, xb.w};
#pragma unroll
        for (int tt = 0; tt < 4; ++tt) {
            bf16x8 a[4];
#pragma unroll
            for (int rg = 0; rg < 4; ++rg) {
                unsigned int w = u[rg * 2 + (tt >> 1)];
                int idx = (tt & 1) ? (int)(w >> 16) : (int)(w & 0xffffu);
                a[rg] = *reinterpret_cast<const bf16x8*>(&embl[idx]);
            }
            const char* Bb = (const char*)&ldsB[buf][0] + (((tt * 4 + q) * 128 + nl) << 4);
#pragma unroll
            for (int nf = 0; nf < 8; ++nf) {
                bf16x8 b = *reinterpret_cast<const bf16x8*>(Bb + nf * 256);
#pragma unroll
                for (int rg = 0; rg < 4; ++rg)
                    acc[rg][nf] = __builtin_amdgcn_mfma_f32_16x16x32_bf16(a[rg], b, acc[rg][nf], 0, 0, 0);
            }
        }
        xa = xa_n; xb = xb_n;
        __syncthreads();
    }

    // epilogue: C/D layout row = q*4+i (within 16-row group), col = nl
    float* Cp = Cbuf + (size_t)kh * 4194304;
#pragma unroll
    for (int rg = 0; rg < 4; ++rg) {
        int rowb = m0 + wv * 64 + rg * 16 + q * 4;
#pragma unroll
        for (int nf = 0; nf < 8; ++nf) {
            int col = nt * 128 + nf * 16 + nl;
#pragma unroll
            for (int i = 0; i < 4; ++i)
                Cp[(size_t)(rowb + i) * 256 + col] = acc[rg][nf][i];
        }
    }
}

// ---------------------------------------------------------------------------
// reduce: 512 blocks = patches. Sum 4 kh partials (coalesced f32x4), gate,
// max over 32 rows, write 128 channels.
// ---------------------------------------------------------------------------
__global__ void reduce_kernel(const float* __restrict__ Cbuf,
                              const float* __restrict__ b1,
                              const float* __restrict__ b2,
                              float* __restrict__ out) {
    __shared__ f32x4 smC[32 * 64];   // 32 KB: [row32][c4 64]
    __shared__ f32x4 smM[8 * 32];    // 4 KB
    int tid = threadIdx.x, gp = blockIdx.x;
    size_t base = (size_t)gp * 32 * 256;
#pragma unroll
    for (int i = 0; i < 8; ++i) {
        int t = i * 256 + tid;
        int row = t >> 6, c4 = t & 63;
        f32x4 s = {};
#pragma unroll
        for (int kh = 0; kh < 4; ++kh) {
            f32x4 v = *(const f32x4*)(Cbuf + (size_t)kh * 4194304 + base + row * 256 + c4 * 4);
            s += v;
        }
        smC[row * 64 + c4] = s;
    }
    __syncthreads();
    int c4 = tid & 31, rgp = tid >> 5;
    f32x4 bb1 = *(const f32x4*)(b1 + c4 * 4);
    f32x4 bb2 = *(const f32x4*)(b2 + c4 * 4);
    f32x4 m;
    m[0] = m[1] = m[2] = m[3] = -INFINITY;
#pragma unroll
    for (int r = 0; r < 4; ++r) {
        int row = rgp * 4 + r;
        f32x4 a = smC[row * 64 + c4];
        f32x4 b = smC[row * 64 + c4 + 32];
#pragma unroll
        for (int j = 0; j < 4; ++j) {
            float g = (a[j] + bb1[j]) * (1.0f / (1.0f + __expf(-(b[j] + bb2[j]))));
            m[j] = fmaxf(m[j], g);
        }
    }
    smM[rgp * 32 + c4] = m;
    __syncthreads();
    if (tid < 32) {
        f32x4 mm = smM[tid];
#pragma unroll
        for (int r = 1; r < 8; ++r) {
            f32x4 v = smM[r * 32 + tid];
#pragma unroll
            for (int j = 0; j < 4; ++j) mm[j] = fmaxf(mm[j], v[j]);
        }
        *(f32x4*)(out + gp * 128 + tid * 4) = mm;
    }
}

// ---------------------------------------------------------------------------
extern "C" void kernel_launch(void* const* d_in, const int* in_sizes, int n_in,
                              void* d_out, int out_size, void* d_ws, size_t ws_size,
                              hipStream_t stream) {
    const int*   x   = (const int*)d_in[0];
    const float* emb = (const float*)d_in[1];
    const float* w1  = (const float*)d_in[2];
    const float* b1  = (const float*)d_in[3];
    const float* w2  = (const float*)d_in[4];
    const float* b2  = (const float*)d_in[5];
    float* out = (float*)d_out;

    char* ws = (char*)d_ws;
    __bf16*         Wp   = (__bf16*)(ws + WS_WP_OFF);
    __bf16*         embp = (__bf16*)(ws + WS_EMB_OFF);
    unsigned short* xpp  = (unsigned short*)(ws + WS_XP_OFF);
    float*          Cbuf = (float*)(ws + WS_C_OFF);

    prep_w<<<65, 256, 0, stream>>>(w1, w2, emb, (uint4*)Wp, embp);
    prep_x<<<256, 256, 0, stream>>>(x, xpp);
    gemm_kernel<<<512, 256, 0, stream>>>(xpp, Wp, (const uint4*)embp, Cbuf);
    reduce_kernel<<<512, 256, 0, stream>>>(Cbuf, b1, b2, out);
}

// Round 5
// 128.642 us; speedup vs baseline: 1.0997x; 1.0997x over previous
//
#include <hip/hip_runtime.h>
#include <hip/hip_bf16.h>
#include <math.h>

// Dims: B=8, T=1048576, V=257, E=8, C=128, K=512, S=512, N=64
// GEMM view: M=16384, Kdim=4096, Ncols=256 (w1 cols 0-127, w2 cols 128-255)
// R5: Cbuf -> bf16 (halves partial-sum HBM traffic, keeps ksplit=4 occupancy),
//     prep_w/prep_x/emb merged into one kernel (one less launch),
//     reduce reads bf16 with fp32 accumulation. Gemm inner loop unchanged (R4).

typedef __bf16 bf16x8 __attribute__((ext_vector_type(8)));
typedef float  f32x4  __attribute__((ext_vector_type(4)));

// ---------------- ws layout ----------------
// [0,2MB)     Wp bf16 [nt2][sg32][tt4][q4][n128][e8]   (byte = sg*16+tt*4+q)
// [2MB,+8KB)  emb bf16 [257][8]
// [4MB,+16MB) xp u16 [mt64][kh4][st8][wave4][lane64][rg4][tt4]
// [24MB,+32MB) Cbuf bf16 [kh4][16384][256]
#define WS_WP_OFF   0u
#define WS_EMB_OFF  (2u << 20)
#define WS_XP_OFF   (4u << 20)
#define WS_C_OFF    (24u << 20)

__device__ __forceinline__ void load_lds16(const void* g, void* l) {
    __builtin_amdgcn_global_load_lds(
        (const __attribute__((address_space(1))) void*)g,
        (__attribute__((address_space(3))) void*)l,
        16, 0, 0);
}

__device__ __forceinline__ unsigned short f2bf(float f) {   // RTNE
    unsigned u = __builtin_bit_cast(unsigned, f);
    return (unsigned short)((u + 0x7fffu + ((u >> 16) & 1u)) >> 16);
}
__device__ __forceinline__ float bflo(unsigned u) {
    return __builtin_bit_cast(float, u << 16);
}
__device__ __forceinline__ float bfhi(unsigned u) {
    return __builtin_bit_cast(float, u & 0xffff0000u);
}

// ---------------------------------------------------------------------------
// prep (merged): bid<64 -> weight pack; 64<=bid<320 -> x transpose; 320 -> emb
// ---------------------------------------------------------------------------
__global__ void prep_kernel(const float* __restrict__ w1,
                            const float* __restrict__ w2,
                            const float* __restrict__ emb,
                            const int* __restrict__ x,
                            uint4* __restrict__ Wp4,
                            __bf16* __restrict__ embp,
                            unsigned short* __restrict__ xp) {
    __shared__ __align__(16) char smem[256 * 136 * 2];   // 69632 B
    int bid = blockIdx.x, tid = threadIdx.x;
    if (bid >= 64 && bid < 320) {
        // ---- x transpose: 256 blocks = (mt64, kh4) ----
        unsigned short* lds = (unsigned short*)smem;      // [256][136] padded
        int xbid = bid - 64;
        int mt = xbid >> 2, kh = xbid & 3;
        const long src0 = (long)mt * 131072 + kh * 128;
#pragma unroll
        for (int i = 0; i < 32; ++i) {
            int f = i * 256 + tid;                   // int4 id: 8192 total
            int row = f >> 5, c = (f & 31) * 4;
            int4 v = *(const int4*)(x + src0 + (long)row * 512 + c);
            ushort4 s;
            s.x = (unsigned short)v.x; s.y = (unsigned short)v.y;
            s.z = (unsigned short)v.z; s.w = (unsigned short)v.w;
            *(ushort4*)&lds[row * 136 + c] = s;
        }
        __syncthreads();
        unsigned short* dst = xp + (size_t)xbid * 32768;
#pragma unroll
        for (int i = 0; i < 32; ++i) {
            int jc = i * 256 + tid;              // ((st*4+w)*64+lane)*4+rg
            int rg = jc & 3, lane = (jc >> 2) & 63, wv = (jc >> 8) & 3, st = jc >> 10;
            int q = lane >> 4, nl = lane & 15;
            int row = wv * 64 + rg * 16 + nl;
            int cb = st * 16 + q;
            ushort4 s;
            s.x = lds[row * 136 + cb];
            s.y = lds[row * 136 + cb + 4];
            s.z = lds[row * 136 + cb + 8];
            s.w = lds[row * 136 + cb + 12];
            *(ushort4*)&dst[jc * 4] = s;
        }
    } else if (bid < 64) {
        // ---- weight pack: (nt=bid>>5, sg=bid&31), one 32KB stage chunk ----
        __bf16* lds = (__bf16*)smem;                      // [n128][byte16][e8]
        int sg = bid & 31, nt = bid >> 5;
        const float* wsrc = nt ? w2 : w1;
#pragma unroll
        for (int i = 0; i < 16; ++i) {
            int g = i * 256 + tid;
            int j4 = g & 3, pair = g >> 2;
            int e = pair & 7, cl = pair >> 3;
            float4 v = *(const float4*)(wsrc + cl * 4096 + e * 512 + sg * 16 + j4 * 4);
            float vv[4] = {v.x, v.y, v.z, v.w};
#pragma unroll
            for (int jj = 0; jj < 4; ++jj)
                lds[(cl * 16 + j4 * 4 + jj) * 8 + e] = (__bf16)vv[jj];
        }
        __syncthreads();
        const uint4* l4 = (const uint4*)lds;
#pragma unroll
        for (int it = 0; it < 8; ++it) {
            int j = it * 256 + tid;              // chunk = (tt*4+q)*128 + n
            int n = j & 127, q = (j >> 7) & 3, tt = (j >> 9) & 3;
            Wp4[bid * 2048 + j] = l4[n * 16 + tt * 4 + q];
        }
    } else {
        for (int i = tid; i < 2056; i += 256) embp[i] = (__bf16)emb[i];
    }
}

// ---------------------------------------------------------------------------
// gemm: 512 blocks = (mt64, kh4, nt2). BM=256, BN=128, 4 waves, wave 64x128.
// 8 stages of 128 hw-k. B DB 2x32KB staged a full stage ahead; A-frags
// gathered from LDS emb table via coalesced xp index stream. bf16 epilogue.
// ---------------------------------------------------------------------------
__global__ __launch_bounds__(256, 2)
void gemm_kernel(const unsigned short* __restrict__ xp,
                 const __bf16* __restrict__ Wp,
                 const uint4* __restrict__ embp,
                 unsigned short* __restrict__ Cbuf) {
    __shared__ uint4 ldsB[2][2048];   // 2 x 32KB: [tt4][q4][n128][e8]
    __shared__ uint4 embl[257];

    const int tid = threadIdx.x;
    const int wv = tid >> 6, lane = tid & 63;
    const int q = lane >> 4, nl = lane & 15;

    for (int i = tid; i < 257; i += 256) embl[i] = embp[i];

    const int bid = blockIdx.x;
    const int mt = bid >> 3, nt = bid & 1, kh = (bid >> 1) & 3;
    const int m0 = mt << 8;

    const char* WpBase = (const char*)Wp + (size_t)(nt * 32 + kh * 8) * 32768;
    const unsigned short* xpS = xp + (size_t)(mt * 4 + kh) * 32768 + (wv * 64 + lane) * 16;

    {
        const char* src = WpBase + tid * 16;
        char* dstl = (char*)&ldsB[0][0] + tid * 16;
#pragma unroll
        for (int i = 0; i < 8; ++i) load_lds16(src + i * 4096, dstl + i * 4096);
    }
    uint4 xa = *(const uint4*)(xpS);
    uint4 xb = *(const uint4*)(xpS + 8);
    __syncthreads();

    f32x4 acc[4][8] = {};

    for (int st = 0; st < 8; ++st) {
        const int buf = st & 1;
        uint4 xa_n = xa, xb_n = xb;
        if (st < 7) {
            const char* src = WpBase + (size_t)(st + 1) * 32768 + tid * 16;
            char* dstl = (char*)&ldsB[buf ^ 1][0] + tid * 16;
#pragma unroll
            for (int i = 0; i < 8; ++i) load_lds16(src + i * 4096, dstl + i * 4096);
            const unsigned short* xn = xpS + (size_t)(st + 1) * 4096;
            xa_n = *(const uint4*)(xn);
            xb_n = *(const uint4*)(xn + 8);
        }
        const unsigned int u[8] = {xa.x, xa.y, xa.z, xa.w, xb.x, xb.y, xb.z, xb.w};
#pragma unroll
        for (int tt = 0; tt < 4; ++tt) {
            bf16x8 a[4];
#pragma unroll
            for (int rg = 0; rg < 4; ++rg) {
                unsigned int w = u[rg * 2 + (tt >> 1)];
                int idx = (tt & 1) ? (int)(w >> 16) : (int)(w & 0xffffu);
                a[rg] = *reinterpret_cast<const bf16x8*>(&embl[idx]);
            }
            const char* Bb = (const char*)&ldsB[buf][0] + (((tt * 4 + q) * 128 + nl) << 4);
#pragma unroll
            for (int nf = 0; nf < 8; ++nf) {
                bf16x8 b = *reinterpret_cast<const bf16x8*>(Bb + nf * 256);
#pragma unroll
                for (int rg = 0; rg < 4; ++rg)
                    acc[rg][nf] = __builtin_amdgcn_mfma_f32_16x16x32_bf16(a[rg], b, acc[rg][nf], 0, 0, 0);
            }
        }
        xa = xa_n; xb = xb_n;
        __syncthreads();
    }

    // epilogue: bf16 RTNE pack. C/D layout row = q*4+i, col = nl (per 16x16)
    unsigned short* Cp = Cbuf + (size_t)kh * 4194304;
#pragma unroll
    for (int rg = 0; rg < 4; ++rg) {
        int rowb = m0 + wv * 64 + rg * 16 + q * 4;
#pragma unroll
        for (int nf = 0; nf < 8; ++nf) {
            int col = nt * 128 + nf * 16 + nl;
#pragma unroll
            for (int i = 0; i < 4; ++i)
                Cp[(size_t)(rowb + i) * 256 + col] = f2bf(acc[rg][nf][i]);
        }
    }
}

// ---------------------------------------------------------------------------
// reduce: 512 blocks = patches. Sum 4 bf16 kh partials in fp32 (uint4 = 8 bf16
// coalesced), gate, max over 32 rows, write 128 channels.
// ---------------------------------------------------------------------------
__global__ void reduce_kernel(const unsigned short* __restrict__ Cbuf,
                              const float* __restrict__ b1,
                              const float* __restrict__ b2,
                              float* __restrict__ out) {
    __shared__ float smC[32 * 256];   // 32 KB
    __shared__ f32x4 smM[8 * 32];     // 4 KB
    int tid = threadIdx.x, gp = blockIdx.x;
    size_t base = (size_t)gp * 32 * 256;
#pragma unroll
    for (int i = 0; i < 4; ++i) {
        int ch = i * 256 + tid;              // 1024 chunks of 8 bf16
        int row = ch >> 5, c8 = ch & 31;
        float s[8] = {};
#pragma unroll
        for (int kh = 0; kh < 4; ++kh) {
            uint4 v = *(const uint4*)(Cbuf + (size_t)kh * 4194304 + base + row * 256 + c8 * 8);
            s[0] += bflo(v.x); s[1] += bfhi(v.x);
            s[2] += bflo(v.y); s[3] += bfhi(v.y);
            s[4] += bflo(v.z); s[5] += bfhi(v.z);
            s[6] += bflo(v.w); s[7] += bfhi(v.w);
        }
        float* d = &smC[row * 256 + c8 * 8];
        *(f32x4*)d       = f32x4{s[0], s[1], s[2], s[3]};
        *(f32x4*)(d + 4) = f32x4{s[4], s[5], s[6], s[7]};
    }
    __syncthreads();
    int c4 = tid & 31, rgp = tid >> 5;
    f32x4 bb1 = *(const f32x4*)(b1 + c4 * 4);
    f32x4 bb2 = *(const f32x4*)(b2 + c4 * 4);
    f32x4 m;
    m[0] = m[1] = m[2] = m[3] = -INFINITY;
#pragma unroll
    for (int r = 0; r < 4; ++r) {
        int row = rgp * 4 + r;
        f32x4 a = *(const f32x4*)&smC[row * 256 + c4 * 4];
        f32x4 b = *(const f32x4*)&smC[row * 256 + 128 + c4 * 4];
#pragma unroll
        for (int j = 0; j < 4; ++j) {
            float g = (a[j] + bb1[j]) * (1.0f / (1.0f + __expf(-(b[j] + bb2[j]))));
            m[j] = fmaxf(m[j], g);
        }
    }
    smM[rgp * 32 + c4] = m;
    __syncthreads();
    if (tid < 32) {
        f32x4 mm = smM[tid];
#pragma unroll
        for (int r = 1; r < 8; ++r) {
            f32x4 v = smM[r * 32 + tid];
#pragma unroll
            for (int j = 0; j < 4; ++j) mm[j] = fmaxf(mm[j], v[j]);
        }
        *(f32x4*)(out + gp * 128 + tid * 4) = mm;
    }
}

// ---------------------------------------------------------------------------
extern "C" void kernel_launch(void* const* d_in, const int* in_sizes, int n_in,
                              void* d_out, int out_size, void* d_ws, size_t ws_size,
                              hipStream_t stream) {
    const int*   x   = (const int*)d_in[0];
    const float* emb = (const float*)d_in[1];
    const float* w1  = (const float*)d_in[2];
    const float* b1  = (const float*)d_in[3];
    const float* w2  = (const float*)d_in[4];
    const float* b2  = (const float*)d_in[5];
    float* out = (float*)d_out;

    char* ws = (char*)d_ws;
    __bf16*         Wp    = (__bf16*)(ws + WS_WP_OFF);
    __bf16*         embp  = (__bf16*)(ws + WS_EMB_OFF);
    unsigned short* xpp   = (unsigned short*)(ws + WS_XP_OFF);
    unsigned short* Cbuf  = (unsigned short*)(ws + WS_C_OFF);

    prep_kernel<<<321, 256, 0, stream>>>(w1, w2, emb, x, (uint4*)Wp, embp, xpp);
    gemm_kernel<<<512, 256, 0, stream>>>(xpp, Wp, (const uint4*)embp, Cbuf);
    reduce_kernel<<<512, 256, 0, stream>>>(Cbuf, b1, b2, out);
}